// Round 1
// baseline (348.376 us; speedup 1.0000x reference)
//
#include <hip/hip_runtime.h>

#define B_ 256
#define T_ 1024
#define V_ 5000
#define D_ 100
#define H_ 64
#define C_ 2

// ---------------------------------------------------------------------------
// Kernel 1: EW[v][h] = sum_d E[v][d] * W[d][h] + b[h]   (unchanged)
// ---------------------------------------------------------------------------
__global__ __launch_bounds__(256) void ew_kernel(const float* __restrict__ E,
                                                 const float* __restrict__ W,
                                                 const float* __restrict__ bias,
                                                 float* __restrict__ EW) {
    int idx = blockIdx.x * 256 + threadIdx.x;   // 0 .. V_*H_
    if (idx >= V_ * H_) return;
    int h = idx & (H_ - 1);
    int v = idx >> 6;
    float acc = bias[h];
    const float* Erow = E + v * D_;
    #pragma unroll 4
    for (int d = 0; d < D_; ++d) {
        acc = fmaf(Erow[d], W[d * H_ + h], acc);
    }
    EW[idx] = acc;
}

// ---------------------------------------------------------------------------
// Kernel 2: per-batch RNN. One wave per batch element.
// R5 change: U COLUMN LIVES IN 64 VGPRs (loop-invariant!) instead of LDS.
//  - was: 16 ds_read_b128/step re-fetching the same U column every step,
//    ~190 cyc/step of LDS pipe + lgkmcnt waits that a single wave can't hide
//  - now: zero LDS ops in the dot product; pure VALU stream of
//    64 v_readlane + 64 v_fmac + ~10 tail insts, 4 independent acc chains
//    so the scheduler fills readlane->SGPR hazard slots.
//  - sh_U4 (16 KB) dropped; LDS is just the padded token ring (4 KB).
//  - VGPRs: 64 (U) + ~30 state => ~100, fine at 1 wave/SIMD (512 budget).
// Kept from R4: padded sh_tok (no tail guard), 2-step EW prefetch pipeline,
// clampless tanh  hn = 1 - 2*rcp(e^{2x}+1)  (inf->1, 0->-1, no NaN).
// ---------------------------------------------------------------------------
__device__ __forceinline__ float readlane_f(float v, int lane) {
    return __uint_as_float(__builtin_amdgcn_readlane(__float_as_uint(v), lane));
}

__global__ __launch_bounds__(64, 1) void rnn_kernel(const int* __restrict__ tokens,
                                                    const float* __restrict__ EW,
                                                    const float* __restrict__ U,
                                                    const float* __restrict__ Wd,
                                                    const float* __restrict__ bd,
                                                    float* __restrict__ out) {
    const int b = blockIdx.x;     // batch element
    const int j = threadIdx.x;    // 0..63 : hidden unit

    __shared__ int sh_tok[T_ + 2];   // 4 KB + pad (kills tail guard)

    // --- U column j -> registers. u[k] = U[k][j]; coalesced across lanes
    //     for each k (lanes j=0..63 read 256 consecutive bytes). ---
    float u[H_];
    #pragma unroll
    for (int k = 0; k < H_; ++k) {
        u[k] = U[k * H_ + j];
    }

    const int* tok = tokens + b * T_;
    #pragma unroll
    for (int k = 0; k < T_ / H_; ++k) {
        sh_tok[k * H_ + j] = tok[k * H_ + j];    // coalesced
    }
    if (j < 2) sh_tok[T_ + j] = 0;               // pad
    __syncthreads();

    float h = 0.f;
    float pooled = 0.f;

    // 2-step-deep xw prefetch pipeline (covers L2 latency of EW gather)
    int2 tkA = *(const int2*)&sh_tok[0];
    float xw0 = EW[tkA.x * H_ + j];
    float xw1 = EW[tkA.y * H_ + j];

    // one recurrence step: register-resident dot + clampless tanh + mask + pool
    #define RNN_STEP(tokv, xwv)                                          \
    {                                                                    \
        float a0 = 0.f, a1 = 0.f, a2 = 0.f, a3 = 0.f;                    \
        _Pragma("unroll")                                                \
        for (int c = 0; c < 16; ++c) {                                   \
            a0 = fmaf(readlane_f(h, 4 * c + 0), u[4 * c + 0], a0);       \
            a1 = fmaf(readlane_f(h, 4 * c + 1), u[4 * c + 1], a1);       \
            a2 = fmaf(readlane_f(h, 4 * c + 2), u[4 * c + 2], a2);       \
            a3 = fmaf(readlane_f(h, 4 * c + 3), u[4 * c + 3], a3);       \
        }                                                                \
        float x = ((a0 + a1) + (a2 + a3)) + (xwv);                       \
        float e = __expf(2.f * x);                                       \
        float r = __builtin_amdgcn_rcpf(e + 1.f);                        \
        float hn = fmaf(-2.f, r, 1.f);                                   \
        h = ((tokv) != 0) ? hn : h;                                      \
        pooled += h;                                                     \
    }

    for (int t = 0; t < T_; t += 2) {
        // prefetch steps t+2, t+3 (pad makes the tail read safe: EW[0])
        int2 tkB = *(const int2*)&sh_tok[t + 2];
        float xw2 = EW[tkB.x * H_ + j];
        float xw3 = EW[tkB.y * H_ + j];

        RNN_STEP(tkA.x, xw0);
        RNN_STEP(tkA.y, xw1);

        tkA = tkB;
        xw0 = xw2;
        xw1 = xw3;
    }
    #undef RNN_STEP

    // ---- epilogue: pooled mean -> dense(2) -> sigmoid ----
    float p = pooled * (1.0f / (float)T_);
    float v0 = p * Wd[j * C_ + 0];
    float v1 = p * Wd[j * C_ + 1];
    #pragma unroll
    for (int off = 32; off >= 1; off >>= 1) {
        v0 += __shfl_down(v0, off, 64);
        v1 += __shfl_down(v1, off, 64);
    }
    if (j == 0) {
        float l0 = v0 + bd[0];
        float l1 = v1 + bd[1];
        out[b * C_ + 0] = 1.f / (1.f + __expf(-l0));
        out[b * C_ + 1] = 1.f / (1.f + __expf(-l1));
    }
}

// ---------------------------------------------------------------------------
extern "C" void kernel_launch(void* const* d_in, const int* in_sizes, int n_in,
                              void* d_out, int out_size, void* d_ws, size_t ws_size,
                              hipStream_t stream) {
    const int*   tokens = (const int*)  d_in[0];  // [B,T] int32
    const float* E      = (const float*)d_in[1];  // [V,D]
    const float* W      = (const float*)d_in[2];  // [D,H]
    const float* U      = (const float*)d_in[3];  // [H,H]
    const float* bias   = (const float*)d_in[4];  // [H]
    const float* Wd     = (const float*)d_in[5];  // [H,C]
    const float* bd     = (const float*)d_in[6];  // [C]
    float* out = (float*)d_out;                   // [B,C]
    float* EW  = (float*)d_ws;                    // [V,H] scratch: 1.28 MB

    ew_kernel<<<(V_ * H_ + 255) / 256, 256, 0, stream>>>(E, W, bias, EW);
    rnn_kernel<<<B_, H_, 0, stream>>>(tokens, EW, U, Wd, bd, out);
}

// Round 2
// 347.024 us; speedup vs baseline: 1.0039x; 1.0039x over previous
//
#include <hip/hip_runtime.h>

#define B_ 256
#define T_ 1024
#define V_ 5000
#define D_ 100
#define H_ 64
#define C_ 2

// ---------------------------------------------------------------------------
// Kernel 1: EW[v][h] = sum_d E[v][d] * W[d][h] + b[h]   (unchanged)
// ---------------------------------------------------------------------------
__global__ __launch_bounds__(256) void ew_kernel(const float* __restrict__ E,
                                                 const float* __restrict__ W,
                                                 const float* __restrict__ bias,
                                                 float* __restrict__ EW) {
    int idx = blockIdx.x * 256 + threadIdx.x;   // 0 .. V_*H_
    if (idx >= V_ * H_) return;
    int h = idx & (H_ - 1);
    int v = idx >> 6;
    float acc = bias[h];
    const float* Erow = E + v * D_;
    #pragma unroll 4
    for (int d = 0; d < D_; ++d) {
        acc = fmaf(Erow[d], W[d * H_ + h], acc);
    }
    EW[idx] = acc;
}

// ---------------------------------------------------------------------------
// Kernel 2: per-batch RNN. One wave per batch element.
// R6 FIX: R5's "U in registers" never materialized -- VGPR_Count was 72,
// i.e. the allocator re-loaded U from global EVERY STEP (64 loads + addr
// VALU + vmcnt stalls/step; rnn stayed at 279 us == R4).
// The fix: pin each u[k] with an opaque `asm volatile("" : "+v")` after the
// load. The value becomes non-rematerializable, so the allocator MUST keep
// all 64 in VGPRs (budget 512 at launch_bounds(64,1); expect ~160 used).
// Loop body is then pure VALU: 64 v_readlane + 64 v_fmac + ~15 tail insts,
// 4 independent acc chains to cover the readlane->SGPR read latency.
// Kept from R4/R5: padded sh_tok (no tail guard), 2-step EW prefetch
// pipeline, clampless tanh  hn = 1 - 2*rcp(e^{2x}+1)  (inf->1, 0->-1).
// ---------------------------------------------------------------------------
__device__ __forceinline__ float readlane_f(float v, int lane) {
    return __uint_as_float(__builtin_amdgcn_readlane(__float_as_uint(v), lane));
}

__global__ __launch_bounds__(64, 1) void rnn_kernel(const int* __restrict__ tokens,
                                                    const float* __restrict__ EW,
                                                    const float* __restrict__ U,
                                                    const float* __restrict__ Wd,
                                                    const float* __restrict__ bd,
                                                    float* __restrict__ out) {
    const int b = blockIdx.x;     // batch element
    const int j = threadIdx.x;    // 0..63 : hidden unit

    __shared__ int sh_tok[T_ + 2];   // 4 KB + pad (kills tail guard)

    // --- U column j -> 64 VGPRs. u[k] = U[k][j]; coalesced across lanes. ---
    float u[H_];
    #pragma unroll
    for (int k = 0; k < H_; ++k) {
        u[k] = U[k * H_ + j];
    }
    // PIN: make each u[k] opaque so it cannot be rematerialized from memory.
    // This is the whole point of R6 -- without it the allocator dropped the
    // hoist and re-fetched U per step (VGPR_Count 72 in R5's profile).
    #pragma unroll
    for (int k = 0; k < H_; ++k) {
        asm volatile("" : "+v"(u[k]));
    }

    const int* tok = tokens + b * T_;
    #pragma unroll
    for (int k = 0; k < T_ / H_; ++k) {
        sh_tok[k * H_ + j] = tok[k * H_ + j];    // coalesced
    }
    if (j < 2) sh_tok[T_ + j] = 0;               // pad
    __syncthreads();

    float h = 0.f;
    float pooled = 0.f;

    // 2-step-deep xw prefetch pipeline (covers L2 latency of EW gather)
    int2 tkA = *(const int2*)&sh_tok[0];
    float xw0 = EW[tkA.x * H_ + j];
    float xw1 = EW[tkA.y * H_ + j];

    // one recurrence step: register-resident dot + clampless tanh + mask + pool
    #define RNN_STEP(tokv, xwv)                                          \
    {                                                                    \
        float a0 = 0.f, a1 = 0.f, a2 = 0.f, a3 = 0.f;                    \
        _Pragma("unroll")                                                \
        for (int c = 0; c < 16; ++c) {                                   \
            a0 = fmaf(readlane_f(h, 4 * c + 0), u[4 * c + 0], a0);       \
            a1 = fmaf(readlane_f(h, 4 * c + 1), u[4 * c + 1], a1);       \
            a2 = fmaf(readlane_f(h, 4 * c + 2), u[4 * c + 2], a2);       \
            a3 = fmaf(readlane_f(h, 4 * c + 3), u[4 * c + 3], a3);       \
        }                                                                \
        float x = ((a0 + a1) + (a2 + a3)) + (xwv);                       \
        float e = __expf(2.f * x);                                       \
        float r = __builtin_amdgcn_rcpf(e + 1.f);                        \
        float hn = fmaf(-2.f, r, 1.f);                                   \
        h = ((tokv) != 0) ? hn : h;                                      \
        pooled += h;                                                     \
    }

    for (int t = 0; t < T_; t += 2) {
        // prefetch steps t+2, t+3 (pad makes the tail read safe: EW[0])
        int2 tkB = *(const int2*)&sh_tok[t + 2];
        float xw2 = EW[tkB.x * H_ + j];
        float xw3 = EW[tkB.y * H_ + j];

        RNN_STEP(tkA.x, xw0);
        RNN_STEP(tkA.y, xw1);

        tkA = tkB;
        xw0 = xw2;
        xw1 = xw3;
    }
    #undef RNN_STEP

    // ---- epilogue: pooled mean -> dense(2) -> sigmoid ----
    float p = pooled * (1.0f / (float)T_);
    float v0 = p * Wd[j * C_ + 0];
    float v1 = p * Wd[j * C_ + 1];
    #pragma unroll
    for (int off = 32; off >= 1; off >>= 1) {
        v0 += __shfl_down(v0, off, 64);
        v1 += __shfl_down(v1, off, 64);
    }
    if (j == 0) {
        float l0 = v0 + bd[0];
        float l1 = v1 + bd[1];
        out[b * C_ + 0] = 1.f / (1.f + __expf(-l0));
        out[b * C_ + 1] = 1.f / (1.f + __expf(-l1));
    }
}

// ---------------------------------------------------------------------------
extern "C" void kernel_launch(void* const* d_in, const int* in_sizes, int n_in,
                              void* d_out, int out_size, void* d_ws, size_t ws_size,
                              hipStream_t stream) {
    const int*   tokens = (const int*)  d_in[0];  // [B,T] int32
    const float* E      = (const float*)d_in[1];  // [V,D]
    const float* W      = (const float*)d_in[2];  // [D,H]
    const float* U      = (const float*)d_in[3];  // [H,H]
    const float* bias   = (const float*)d_in[4];  // [H]
    const float* Wd     = (const float*)d_in[5];  // [H,C]
    const float* bd     = (const float*)d_in[6];  // [C]
    float* out = (float*)d_out;                   // [B,C]
    float* EW  = (float*)d_ws;                    // [V,H] scratch: 1.28 MB

    ew_kernel<<<(V_ * H_ + 255) / 256, 256, 0, stream>>>(E, W, bias, EW);
    rnn_kernel<<<B_, H_, 0, stream>>>(tokens, EW, U, Wd, bd, out);
}